// Round 13
// baseline (256.521 us; speedup 1.0000x reference)
//
#include <hip/hip_runtime.h>
#include <hip/hip_bf16.h>
#include <math.h>

#define NB 16
#define ND 256
#define NL 200
#define NT 1000

typedef unsigned short ushort_t;
typedef __bf16 bf16x8 __attribute__((ext_vector_type(8)));
typedef float f32x4 __attribute__((ext_vector_type(4)));

// ---- workspace layout (float offsets) ----
#define OFF_FL    4981936u   // frame_lengths int            16
#define OFF_GT    11535552u  // Gt bf16 [b][256][800]        1638400 floats
#define OFF_WOT   15221952u  // WoT bf16 [512][256]          65536 floats
#define OFF_BASE  15287488u  // base[b][256][8] fp32         32768 floats

__device__ __forceinline__ float silu_f(float x){ return x / (1.f + __expf(-x)); }
__device__ __forceinline__ ushort_t f2bf(float x){
  __hip_bfloat16 h = __float2bfloat16(x);
  return *(ushort_t*)&h;
}

// ========== KERNEL A: conv+base(256) | gemmG(256) | prep(16) | WoTpack(128) ====
// LDS dieted to 39,936 B -> 4 blocks/CU (16 waves) vs previous 2 (8 waves):
// k_A was latency-bound (Occ 11.8%, VALU 22%, HBM 4%) — double the TLP.
// conv: branches sequential sharing one U buffer (same FMA order per branch).
// gemmG: K staged in quarters (same values, same accumulation order).
__global__ __launch_bounds__(256, 4) void k_A(
    const float* __restrict__ dur, const float* __restrict__ ph,
    const float* __restrict__ Wp_w, const float* __restrict__ C_w, const float* __restrict__ bp_w,
    const float* __restrict__ Wp_c, const float* __restrict__ C_c, const float* __restrict__ bp_c,
    const float* __restrict__ Wo, const float* __restrict__ Lw,
    const float* __restrict__ cbw, const float* __restrict__ cbc,
    const float* __restrict__ Mw, const float* __restrict__ mbw,
    const float* __restrict__ Mc, const float* __restrict__ mbc,
    int* __restrict__ fl_ws, float* __restrict__ o_fm, float* __restrict__ o_fl,
    ushort_t* __restrict__ WoT, float4* __restrict__ base,
    ushort_t* __restrict__ Gt)
{
  __shared__ __align__(16) unsigned char smem[39936];
  int bid = blockIdx.x, tid = threadIdx.x;

  if (bid < 256){
    // ================= conv + base, sequential branches =================
    int b = bid >> 4, x = bid & 15;
    if (x >= 13){
      int l0 = 208 + (x - 13)*16;
      if (tid < 32)
        base[((size_t)(b*256 + l0 + (tid >> 1)))*2 + (tid & 1)] = make_float4(0,0,0,0);
      return;
    }
    float* phs  = (float*)smem;                   // [18][256]  18432 B
    float* U    = (float*)(smem + 18432);         // [256][18]  18432 B
    float* ssk  = (float*)(smem + 36864);         // 256 f      1024 B
    float (*sh)[16] = (float (*)[16])(smem + 37888); // 16x16   1024 B
    float* sdur = (float*)(smem + 38912);         // 256 f      1024 B
    int l0 = x*16;

    sdur[tid & 255] = 0.f;
    __syncthreads();
    if (tid < NL) sdur[tid] = dur[b*NL + tid];
    __syncthreads();
    if (tid == 0){
      float run = 0.f;
      for (int l = 0; l < NL; ++l){ ssk[l] = run; run += sdur[l]; }
    }
    // ---- stage ph slice: phs[j][d], j -> l = l0-1+j ----
    {
      const float* pr = ph + ((size_t)b*ND + tid)*NL;
      #pragma unroll
      for (int j = 0; j < 18; ++j){
        int l = l0 - 1 + j;
        phs[j*256 + tid] = (l >= 0 && l < NL) ? pr[l] : 0.f;
      }
    }
    __syncthreads();

    for (int br = 0; br < 2; ++br){
      const float* Wp  = br ? Wp_c : Wp_w;
      const float* bpv = br ? bp_c : bp_w;
      // ---- U = Wp * phs + bp, thread = i ----
      {
        int i = tid;
        float u[18];
        float bb = bpv[i];
        #pragma unroll
        for (int j = 0; j < 18; ++j) u[j] = bb;
        const float4* wr = (const float4*)(Wp + (size_t)i*ND);
        for (int d4 = 0; d4 < 64; ++d4){
          float4 a = wr[d4];
          #pragma unroll
          for (int j = 0; j < 18; ++j){
            float4 p = *(const float4*)&phs[j*256 + d4*4];
            u[j] += a.x*p.x + a.y*p.y + a.z*p.z + a.w*p.w;
          }
        }
        #pragma unroll
        for (int j = 0; j < 18; ++j){
          int l = l0 - 1 + j;
          bool pad = (l < 0 || l >= NL);     // SAME zero-pad: conv input is 0
          U[i*18 + j] = pad ? 0.f : u[j];
        }
      }
      __syncthreads();
      // ---- conv over channels + silu + mask: threads (lu,oc) ----
      if (tid < 128){
        int lu = tid >> 3, oc = tid & 7;
        int l = l0 + lu;
        float h = 0.f;
        if (l < NL){
          const float* C = br ? C_c : C_w;
          float val = (br ? cbc : cbw)[oc];
          #pragma unroll 4
          for (int i = 0; i < ND; ++i){
            const float* cc = C + ((size_t)oc*ND + i)*3;
            val += cc[0]*U[i*18 + lu] + cc[1]*U[i*18 + lu + 1] + cc[2]*U[i*18 + lu + 2];
          }
          float pm = (sdur[l] > 0.5f) ? 1.f : 0.f;
          h = silu_f(val) * pm;
        }
        sh[lu][br*8 + oc] = h;
      }
      __syncthreads();   // before U reuse / epilogue
    }
    // ---- base/MLP epilogue (identical math) ----
    if (tid < 16){
      int ll = x*16 + tid;
      float4 o0 = make_float4(0,0,0,0);
      float4 o1 = make_float4(0,0,0,0);
      if (ll < NL){
        float dl  = sdur[ll];
        float pm  = (dl > 0.5f) ? 1.f : 0.f;
        float skl = ssk[ll];
        float c1[4], c2[2];
        #pragma unroll
        for (int q = 0; q < 4; ++q) c1[q] = mbw[q] + dl*Mw[4 + q] - skl*Mw[q];
        #pragma unroll
        for (int p = 0; p < 2; ++p) c2[p] = mbc[p] + dl*Mc[2 + p] - skl*Mc[p];
        #pragma unroll
        for (int j = 0; j < 8; ++j){
          float hwv = sh[tid][j], hcv = sh[tid][8 + j];
          #pragma unroll
          for (int q = 0; q < 4; ++q) c1[q] += hwv*Mw[(2 + j)*4 + q];
          #pragma unroll
          for (int p = 0; p < 2; ++p) c2[p] += hcv*Mc[(2 + j)*2 + p];
        }
        o0 = make_float4(c1[0], c1[1], c1[2], c1[3]);
        o1 = make_float4(c2[0], c2[1], pm, 0.f);
      }
      base[((size_t)(b*256 + ll))*2 + 0] = o0;
      base[((size_t)(b*256 + ll))*2 + 1] = o1;
    }
  } else if (bid < 512){
    // ================= Gt = Lw x ph (per b,q), K-quarter staging =============
    int r = bid - 256;                   // (xb, yb, b, q)
    int xb = r & 1, yb = (r >> 1) & 1, bq = r >> 2;
    int b = bq >> 2, q = bq & 3;
    int m0 = yb * 128;                   // n dim
    int n0 = xb * 128;                   // l dim
    int lane = tid & 63, wave = tid >> 6;
    int wm = wave >> 1, wn = wave & 1;
    int col = lane & 15, kg4 = lane >> 4;
    ushort_t (*Asub)[72] = (ushort_t (*)[72])smem;             // 18432 B
    ushort_t (*Bsub)[72] = (ushort_t (*)[72])(smem + 18432);   // 18432 B
    int na = lane*2;                     // n-pair this lane owns

    f32x4 acc[4][4] = {};
    for (int kq = 0; kq < 4; ++kq){
      int d0 = kq*64;
      // ---- A: row dk read coalesced (512B/wave), written transposed ----
      for (int rep = 0; rep < 16; ++rep){
        int dk = wave*16 + rep;
        float2 v = *(const float2*)(Lw + ((size_t)(q*256 + d0 + dk))*ND + m0 + na);
        Asub[na    ][dk] = f2bf(v.x);
        Asub[na + 1][dk] = f2bf(v.y);
      }
      // ---- B: row dk read coalesced, l >= NL zero-padded ----
      for (int rep = 0; rep < 16; ++rep){
        int dk = wave*16 + rep;
        int l = n0 + na;
        float2 v; v.x = 0.f; v.y = 0.f;
        if (l < NL)
          v = *(const float2*)(ph + ((size_t)b*ND + d0 + dk)*NL + l);
        Bsub[na    ][dk] = f2bf(v.x);
        Bsub[na + 1][dk] = f2bf(v.y);
      }
      __syncthreads();
      // ---- MFMA over this quarter-K ----
      for (int kt = 0; kt < 2; ++kt){
        int k0 = kt*32;
        bf16x8 afr[4], bfr[4];
        #pragma unroll
        for (int i = 0; i < 4; ++i)
          afr[i] = *(const bf16x8*)&Asub[wm*64 + i*16 + col][k0 + kg4*8];
        #pragma unroll
        for (int j = 0; j < 4; ++j)
          bfr[j] = *(const bf16x8*)&Bsub[wn*64 + j*16 + col][k0 + kg4*8];
        #pragma unroll
        for (int i = 0; i < 4; ++i)
          #pragma unroll
          for (int j = 0; j < 4; ++j)
            acc[i][j] = __builtin_amdgcn_mfma_f32_16x16x32_bf16(afr[i], bfr[j], acc[i][j], 0, 0, 0);
      }
      __syncthreads();
    }
    // ---- stage output tile in LDS (overlays Asub+Bsub), coalesced stores ----
    ushort_t (*st2)[136] = (ushort_t (*)[136])smem;            // 34816 B
    int rq = lane >> 4;
    #pragma unroll
    for (int i = 0; i < 4; ++i){
      #pragma unroll
      for (int rr = 0; rr < 4; ++rr){
        int rl = wm*64 + i*16 + rq*4 + rr;
        #pragma unroll
        for (int j = 0; j < 4; ++j){
          int cl = wn*64 + j*16 + col;
          st2[rl][cl] = f2bf(acc[i][j][rr]);
        }
      }
    }
    __syncthreads();
    #pragma unroll
    for (int rep = 0; rep < 8; ++rep){
      int row = rep*16 + (tid >> 4);
      int ch  = tid & 15;
      int l   = n0 + ch*8;
      if (l < NL){
        int n = m0 + row;
        *(uint4*)(Gt + ((size_t)(b*ND + n))*800 + q*NL + l) = *(const uint4*)&st2[row][ch*8];
      }
    }
  } else if (bid < 528){
    // ================= prep: cumsum -> fl, frame_mask =================
    int b = bid - 512;
    float* sdur = (float*)smem;
    int* sfl = (int*)(sdur + 256);
    if (tid < NL) sdur[tid] = dur[b*NL + tid];
    __syncthreads();
    if (tid == 0){
      float run = 0.f;
      for (int l = 0; l < NL; ++l) run += sdur[l];
      int fl = (int)rintf(run);          // round-half-even, matches jnp.round
      fl = fl < 0 ? 0 : (fl > NT ? NT : fl);
      sfl[0] = fl; fl_ws[b] = fl; o_fl[b] = (float)fl;
    }
    __syncthreads();
    int flv = sfl[0];
    for (int t = tid; t < NT; t += 256) o_fm[b*NT + t] = (t < flv) ? 1.f : 0.f;
  } else {
    // ================= WoT pack: WoT[n][k] = Wo[k][n] bf16 =================
    int base_id = (bid - 528)*256 + tid;
    #pragma unroll
    for (int rep = 0; rep < 4; ++rep){
      int gid = rep*32768 + base_id;     // 131072 total
      int n = gid >> 8, k = gid & 255;
      WoT[gid] = f2bf(Wo[(size_t)k*512 + n]);
    }
  }
}

// =========== K3: FUSED softmax + V-GEMM + out-GEMM per (b, 64-t tile) ==========
// TT=64, 1024 threads (16 waves), grid (16,16) = 256 blocks = exactly 1/CU.
// (R10/R12 static version, verbatim — wv restructuring closed.)
#define AP 808
#define TT 64
__global__ __launch_bounds__(1024, 4) void k_wv_fused(
    const float4* __restrict__ base,
    const int* __restrict__ fl_ws,
    const float* __restrict__ Mw, const float* __restrict__ Mc,
    const ushort_t* __restrict__ Gt,    // [16][256][800] bf16
    const float* __restrict__ Lc,       // [8][256]
    const float* __restrict__ lbc,      // [256]
    const float* __restrict__ lbw,      // [256]
    const ushort_t* __restrict__ WoT,   // [512][256] bf16
    const float* __restrict__ bo,       // [512]
    float* __restrict__ wout,
    float* __restrict__ o_mean, float* __restrict__ o_lstd)
{
  __shared__ ushort_t As[TT*AP];   // 103.4 KB w-tile [t_local][k=q*200+l]
  __shared__ float    wcs[TT][8];  // 2 KB per-t wc
  int b = blockIdx.x;              // batch -> XCD = b%8
  int m0 = blockIdx.y * TT;        // t tile (16 tiles cover 0..1023)
  int tid = threadIdx.x, lane = tid & 63, wave = tid >> 6;   // 16 waves
  int col = lane & 15, kg4 = lane >> 4;
  int fl = fl_ws[b];

  // ---------------- early-out: fully-masked tile ----------------
  if (fl <= m0){
    for (int idx = tid; idx < TT*4*50; idx += 1024){
      int tl = idx / 200;
      int rqs = idx - tl*200;
      int q = rqs / 50, seg = rqs - q*50;
      int t = m0 + tl;
      if (t < NT)
        *(float4*)&wout[(((size_t)(b*4 + q))*NT + t)*NL + seg*4] = make_float4(0,0,0,0);
    }
    for (int idx = tid; idx < 512*16; idx += 1024){
      int s = idx >> 4, j = idx & 15;
      int t0 = m0 + j*4;
      if (t0 + 3 < NT){
        float v = bo[s];
        float4 v4 = make_float4(v, v, v, v);
        if (s < ND) *(float4*)&o_mean[((size_t)b*ND + s)*NT + t0] = v4;
        else        *(float4*)&o_lstd[((size_t)b*ND + (s - ND))*NT + t0] = v4;
      }
    }
    return;
  }

  // ---------------- phase 1: softmax, lane owns l = lane*4..lane*4+3 ----------
  int l0 = lane*4;
  bool lv = (l0 < NL);             // lanes 0..49 active

  #pragma unroll
  for (int s = 0; s < 4; ++s){
    int tl = wave*4 + s, t = m0 + tl;
    if (t < fl) continue;
    for (int k = l0; k < 800; k += 256){
      uint2 zz2; zz2.x = 0u; zz2.y = 0u;
      *(uint2*)&As[tl*AP + k] = zz2;
    }
    if (lane < 8) wcs[tl][lane] = 0.f;
    if (t < NT && lv){
      float4 z4 = make_float4(0,0,0,0);
      #pragma unroll
      for (int q = 0; q < 4; ++q)
        *(float4*)&wout[(((size_t)(b*4 + q))*NT + t)*NL + l0] = z4;
    }
  }

  float b0a[4][4], b1x[4], b1y[4], pmv[4];
  #pragma unroll
  for (int e = 0; e < 4; ++e){
    float4 v0 = make_float4(0,0,0,0), v1 = make_float4(0,0,0,0);
    if (lv){
      v0 = base[((size_t)(b*256 + l0 + e))*2 + 0];
      v1 = base[((size_t)(b*256 + l0 + e))*2 + 1];
    }
    b0a[e][0] = v0.x; b0a[e][1] = v0.y; b0a[e][2] = v0.z; b0a[e][3] = v0.w;
    b1x[e] = v1.x; b1y[e] = v1.y; pmv[e] = v1.z;
  }
  float mwq[4] = {Mw[0], Mw[1], Mw[2], Mw[3]};
  float mcp[2] = {Mc[0], Mc[1]};

  for (int sp = 0; sp < 2; ++sp){
    int tl0 = wave*4 + sp*2;
    int t0 = m0 + tl0;
    if (t0 >= fl) break;
    bool a1 = (t0 + 1 < fl);
    float tf[2] = {(float)(t0 + 1), (float)(t0 + 2)};

    float z[2][4][4], mx[2][4];
    #pragma unroll
    for (int u = 0; u < 2; ++u)
      #pragma unroll
      for (int q = 0; q < 4; ++q) mx[u][q] = -INFINITY;
    #pragma unroll
    for (int e = 0; e < 4; ++e){
      #pragma unroll
      for (int u = 0; u < 2; ++u){
        #pragma unroll
        for (int q = 0; q < 4; ++q){
          float sv = silu_f(b0a[e][q] + tf[u]*mwq[q]);
          float zv = (pmv[e] > 0.f) ? sv : -INFINITY;
          z[u][e][q] = zv;
          mx[u][q] = fmaxf(mx[u][q], zv);
        }
      }
    }
    #pragma unroll
    for (int u = 0; u < 2; ++u)
      #pragma unroll
      for (int q = 0; q < 4; ++q){
        float v = mx[u][q];
        #pragma unroll
        for (int off = 32; off; off >>= 1) v = fmaxf(v, __shfl_xor(v, off));
        mx[u][q] = v;
      }
    float is4[2][4] = {{0,0,0,0},{0,0,0,0}};
    #pragma unroll
    for (int e = 0; e < 4; ++e){
      #pragma unroll
      for (int u = 0; u < 2; ++u){
        #pragma unroll
        for (int q = 0; q < 4; ++q){
          float ev = (pmv[e] > 0.f) ? __expf(z[u][e][q] - mx[u][q]) : 0.f;
          z[u][e][q] = ev;
          is4[u][q] += ev;
        }
      }
    }
    #pragma unroll
    for (int u = 0; u < 2; ++u)
      #pragma unroll
      for (int q = 0; q < 4; ++q){
        float v = is4[u][q];
        #pragma unroll
        for (int off = 32; off; off >>= 1) v += __shfl_xor(v, off);
        is4[u][q] = 1.f / v;
      }
    float cv[2][4][2];
    #pragma unroll
    for (int e = 0; e < 4; ++e)
      #pragma unroll
      for (int u = 0; u < 2; ++u){
        cv[u][e][0] = silu_f(b1x[e] + tf[u]*mcp[0]);
        cv[u][e][1] = silu_f(b1y[e] + tf[u]*mcp[1]);
      }
    float wc[2][8];
    #pragma unroll
    for (int u = 0; u < 2; ++u)
      #pragma unroll
      for (int x = 0; x < 8; ++x) wc[u][x] = 0.f;
    #pragma unroll
    for (int u = 0; u < 2; ++u){
      bool act = (u == 0) || a1;
      int t = t0 + u, tl = tl0 + u;
      #pragma unroll
      for (int q = 0; q < 4; ++q){
        float w0 = z[u][0][q]*is4[u][q];
        float w1 = z[u][1][q]*is4[u][q];
        float w2 = z[u][2][q]*is4[u][q];
        float w3 = z[u][3][q]*is4[u][q];
        if (act && lv){
          *(float4*)&wout[(((size_t)(b*4 + q))*NT + t)*NL + l0] =
              make_float4(w0, w1, w2, w3);
          uint2 pk;
          pk.x = (unsigned)f2bf(w0) | ((unsigned)f2bf(w1) << 16);
          pk.y = (unsigned)f2bf(w2) | ((unsigned)f2bf(w3) << 16);
          *(uint2*)&As[tl*AP + q*NL + l0] = pk;
        }
        wc[u][q*2 + 0] += w0*cv[u][0][0] + w1*cv[u][1][0] + w2*cv[u][2][0] + w3*cv[u][3][0];
        wc[u][q*2 + 1] += w0*cv[u][0][1] + w1*cv[u][1][1] + w2*cv[u][2][1] + w3*cv[u][3][1];
      }
    }
    #pragma unroll
    for (int u = 0; u < 2; ++u){
      if (u == 1 && !a1) break;
      #pragma unroll
      for (int x = 0; x < 8; ++x){
        float v = wc[u][x];
        #pragma unroll
        for (int off = 32; off; off >>= 1) v += __shfl_xor(v, off);
        wc[u][x] = v;
      }
      if (lane == 0){
        #pragma unroll
        for (int x = 0; x < 8; ++x) wcs[tl0 + u][x] = wc[u][x];
      }
    }
  }
  __syncthreads();

  // ------- phase 2: MFMA over K=800; each wave owns 16 Gt rows, 4 t-tiles -----
  f32x4 acc[4] = {};
  const ushort_t* Gb = Gt + (size_t)b*ND*800;
  for (int kt = 0; kt < 25; ++kt){
    int k0 = kt*32;
    bf16x8 afr[4], bfr;
    #pragma unroll
    for (int i = 0; i < 4; ++i)
      afr[i] = *(const bf16x8*)(&As[(i*16 + col)*AP + k0 + kg4*8]);
    bfr = *(const bf16x8*)(Gb + ((size_t)(wave*16 + col))*800 + k0 + kg4*8);
    #pragma unroll
    for (int i = 0; i < 4; ++i)
      acc[i] = __builtin_amdgcn_mfma_f32_16x16x32_bf16(afr[i], bfr, acc[i], 0, 0, 0);
  }
  __syncthreads();   // all waves done reading As -> safe to reuse as whc tile

  // ---- epilogue: whc[t][n] = fm*(vh + lbw + (lbc + wc.Lc)) -> LDS (stc) ----
  ushort_t (*stc)[264] = (ushort_t (*)[264])As;   // 64 x 264 bf16 (33.8KB)
  {
    int rq = lane >> 4;
    int n = wave*16 + col;
    float lbn = lbc[n], lbwn = lbw[n];
    float lcn[8];
    #pragma unroll
    for (int u = 0; u < 8; ++u) lcn[u] = Lc[u*ND + n];
    #pragma unroll
    for (int i = 0; i < 4; ++i){
      #pragma unroll
      for (int r = 0; r < 4; ++r){
        int tl = i*16 + rq*4 + r;
        int t = m0 + tl;
        if (t < NT){
          float f = (t < fl) ? 1.f : 0.f;
          float vcv = lbn
            + wcs[tl][0]*lcn[0] + wcs[tl][1]*lcn[1]
            + wcs[tl][2]*lcn[2] + wcs[tl][3]*lcn[3]
            + wcs[tl][4]*lcn[4] + wcs[tl][5]*lcn[5]
            + wcs[tl][6]*lcn[6] + wcs[tl][7]*lcn[7];
          stc[tl][n] = f2bf(f * (acc[i][r] + lbwn + vcv));
        }
      }
    }
  }
  __syncthreads();   // stc tile complete

  // -------- phase 3: out = WoT x stc^T (512 x 64 per block), from LDS --------
  {
    f32x4 acc2[2][4] = {};
    for (int kt = 0; kt < 8; ++kt){
      int k0 = kt*32;
      bf16x8 afr[2], bfr[4];
      #pragma unroll
      for (int j = 0; j < 4; ++j)
        bfr[j] = *(const bf16x8*)(&stc[j*16 + col][k0 + kg4*8]);
      #pragma unroll
      for (int i = 0; i < 2; ++i)
        afr[i] = *(const bf16x8*)(WoT + ((size_t)(wave*32 + i*16 + col))*ND + k0 + kg4*8);
      #pragma unroll
      for (int i = 0; i < 2; ++i)
        #pragma unroll
        for (int j = 0; j < 4; ++j)
          acc2[i][j] = __builtin_amdgcn_mfma_f32_16x16x32_bf16(afr[i], bfr[j], acc2[i][j], 0, 0, 0);
    }
    int rq = lane >> 4;
    #pragma unroll
    for (int i = 0; i < 2; ++i){
      #pragma unroll
      for (int r = 0; r < 4; ++r){
        int s = wave*32 + i*16 + rq*4 + r;
        float bov = bo[s];
        #pragma unroll
        for (int j = 0; j < 4; ++j){
          int t = m0 + j*16 + col;
          if (t < NT){
            float v = acc2[i][j][r] + bov;
            if (s < ND) o_mean[((size_t)b*ND + s)*NT + t] = v;
            else        o_lstd[((size_t)b*ND + (s - ND))*NT + t] = v;
          }
        }
      }
    }
  }
}

extern "C" void kernel_launch(void* const* d_in, const int* in_sizes, int n_in,
                              void* d_out, int out_size, void* d_ws, size_t ws_size,
                              hipStream_t stream)
{
  const float* dur = (const float*)d_in[0];
  const float* ph  = (const float*)d_in[1];
  // d_in[2] phoneme_mask: unused (pm == durations > 0)
  const float* Wpw = (const float*)d_in[3];
  const float* bpw = (const float*)d_in[4];
  const float* Cw  = (const float*)d_in[5];
  const float* cbw = (const float*)d_in[6];
  const float* Mw  = (const float*)d_in[7];
  const float* mbw = (const float*)d_in[8];
  const float* Lw  = (const float*)d_in[9];
  const float* lbw = (const float*)d_in[10];
  const float* Wpc = (const float*)d_in[11];
  const float* bpc = (const float*)d_in[12];
  const float* Cc  = (const float*)d_in[13];
  const float* cbc = (const float*)d_in[14];
  const float* Mc  = (const float*)d_in[15];
  const float* mbc = (const float*)d_in[16];
  const float* Lc  = (const float*)d_in[17];
  const float* lbc = (const float*)d_in[18];
  const float* Wo  = (const float*)d_in[19];
  const float* bo  = (const float*)d_in[20];

  float* out    = (float*)d_out;
  float* o_mean = out;
  float* o_lstd = out + (size_t)NB*ND*NT;
  float* o_fm   = o_lstd + (size_t)NB*ND*NT;
  float* o_fl   = o_fm + NB*NT;
  float* o_w    = o_fl + NB;

  float* ws   = (float*)d_ws;
  int*   fl   = (int*)(ws + OFF_FL);
  ushort_t* Gt   = (ushort_t*)(ws + OFF_GT);
  ushort_t* WoT  = (ushort_t*)(ws + OFF_WOT);
  float4*   base = (float4*)(ws + OFF_BASE);

  k_A<<<656, 256, 0, stream>>>(dur, ph, Wpw, Cw, bpw, Wpc, Cc, bpc, Wo, Lw,
                               cbw, cbc, Mw, mbw, Mc, mbc,
                               fl, o_fm, o_fl, WoT, base, Gt);
  {
    dim3 g(NB, 16);   // flat id = b + 16*ttile  ->  XCD(id%8) = b%8
    k_wv_fused<<<g, 1024, 0, stream>>>(base, fl, Mw, Mc, Gt, Lc, lbc, lbw,
                                       WoT, bo, o_w, o_mean, o_lstd);
  }
}

// Round 14
// 239.068 us; speedup vs baseline: 1.0730x; 1.0730x over previous
//
#include <hip/hip_runtime.h>
#include <hip/hip_bf16.h>
#include <math.h>

#define NB 16
#define ND 256
#define NL 200
#define NT 1000

typedef unsigned short ushort_t;
typedef __bf16 bf16x8 __attribute__((ext_vector_type(8)));
typedef float f32x4 __attribute__((ext_vector_type(4)));

// ---- workspace layout (float offsets) ----
#define OFF_PHT   0u         // phT[b][l][d] fp32            819200
#define OFF_SK    4966400u   // exclusive cumsum             3200
#define OFF_EW    4969600u   // E[oc][k][d]                  6144
#define OFF_EC    4975744u   //                              6144
#define OFF_BW2   4981888u   //                              24
#define OFF_BC2   4981912u   //                              24
#define OFF_FL    4981936u   // frame_lengths int            16
#define OFF_GT    11535552u  // Gt bf16 [b][256][800]        1638400 floats
#define OFF_WOT   15221952u  // WoT bf16 [512][256]          65536 floats
#define OFF_BASE  15287488u  // base[b][256][8] fp32         32768 floats
#define OFF_PHTB  15320256u  // phTb bf16 [b][256pad][256]   524288 floats
#define OFF_LWT   15844544u  // LwT bf16 [4][256][256]       131072 floats

__device__ __forceinline__ float silu_f(float x){ return x / (1.f + __expf(-x)); }
__device__ __forceinline__ ushort_t f2bf(float x){
  __hip_bfloat16 h = __float2bfloat16(x);
  return *(ushort_t*)&h;
}

// =========== STAGE 1: prep(16) | setup(1584) | transpose(1024) = 2624 blocks ===
__global__ __launch_bounds__(256) void k_stage1(
    const float* __restrict__ dur, const float* __restrict__ ph,
    const float* __restrict__ Wp_w, const float* __restrict__ C_w, const float* __restrict__ bp_w,
    const float* __restrict__ Wp_c, const float* __restrict__ C_c, const float* __restrict__ bp_c,
    const float* __restrict__ Wo, const float* __restrict__ Lw,
    float* __restrict__ sk_ws, int* __restrict__ fl_ws,
    float* __restrict__ o_fm, float* __restrict__ o_fl,
    float* __restrict__ Ew, float* __restrict__ Ec,
    float* __restrict__ bw2, float* __restrict__ bc2,
    ushort_t* __restrict__ WoT, ushort_t* __restrict__ LwT,
    float* __restrict__ phT, ushort_t* __restrict__ phTb)
{
  int bid = blockIdx.x, tid = threadIdx.x;
  if (bid < 16){
    // ---- prep: cumsum, frame_lengths, frame_mask ----
    int b = bid;
    __shared__ float sdur[NL];
    __shared__ float ssk[NL];
    __shared__ int sfl;
    if (tid < NL) sdur[tid] = dur[b*NL + tid];
    __syncthreads();
    if (tid == 0){
      float run = 0.f;
      for (int l = 0; l < NL; ++l){ ssk[l] = run; run += sdur[l]; }
      int fl = (int)rintf(run);          // round-half-even, matches jnp.round
      fl = fl < 0 ? 0 : (fl > NT ? NT : fl);
      sfl = fl; fl_ws[b] = fl; o_fl[b] = (float)fl;
    }
    __syncthreads();
    if (tid < NL) sk_ws[b*NL + tid] = ssk[tid];
    for (int t = tid; t < NT; t += 256) o_fm[b*NT + t] = (t < sfl) ? 1.f : 0.f;
  } else if (bid < 1600){
    // ---- setup: conv-fold E/bias2 + WoT/LwT bf16 packs ----
    int sbid = bid - 16;
    if (sbid < 48){
      int gid = sbid*256 + tid;          // 12288 = 2 * 8*3*256
      int branch = gid / 6144;
      int r = gid % 6144;
      int d = r & 255;
      int ock = r >> 8;                  // oc*3+k
      int oc = ock / 3, k = ock % 3;
      const float* Wp = branch ? Wp_c : Wp_w;
      const float* C  = branch ? C_c  : C_w;
      float acc = 0.f;
      for (int i = 0; i < ND; ++i) acc += C[(oc*ND + i)*3 + k] * Wp[i*ND + d];
      (branch ? Ec : Ew)[r] = acc;
      if (d == 0){
        const float* bp = branch ? bp_c : bp_w;
        float bb = 0.f;
        for (int i = 0; i < ND; ++i) bb += C[(oc*ND + i)*3 + k] * bp[i];
        (branch ? bc2 : bw2)[ock] = bb;
      }
    } else {
      int gid = (sbid - 48)*256 + tid;   // 393216
      if (gid < 131072){
        int n = gid >> 8, k = gid & 255;
        WoT[gid] = f2bf(Wo[(size_t)k*512 + n]);
      } else {
        int r = gid - 131072;            // q*65536 + n*256 + d
        int d = r & 255;
        int qn = r >> 8;
        int q = qn >> 8, n = qn & 255;
        LwT[r] = f2bf(Lw[((size_t)q*256 + d)*256 + n]);
      }
    }
  } else {
    // ---- transpose: ph (b,d,l) -> phT fp32 + phTb bf16 (l padded to 256) ----
    int r = bid - 1600;                  // 1024 = 8 x 8 x 16
    int xb = r & 7, yb = (r >> 3) & 7, b = r >> 6;
    int l0 = xb*32, d0 = yb*32;
    int tx = tid & 31, ty = tid >> 5;    // 32 x 8
    __shared__ float tile[32][33];
    #pragma unroll
    for (int i = 0; i < 4; ++i){
      int d = d0 + ty + i*8, l = l0 + tx;
      tile[ty + i*8][tx] = (l < NL) ? ph[((size_t)b*ND + d)*NL + l] : 0.f;
    }
    __syncthreads();
    #pragma unroll
    for (int i = 0; i < 4; ++i){
      int l = l0 + ty + i*8, d = d0 + tx;
      float v = tile[tx][ty + i*8];
      if (l < NL) phT[((size_t)b*NL + l)*ND + d] = v;
      phTb[((size_t)b*256 + l)*ND + d] = f2bf(v);   // rows >=200 zero
    }
  }
}

// =========== STAGE 2: hwc2+base(256) | gemmG(256, LDS-staged stores) ===========
__global__ __launch_bounds__(256) void k_stage2(
    const float* __restrict__ phT,
    const float* __restrict__ dur, const float* __restrict__ sk_ws,
    const float* __restrict__ Ew, const float* __restrict__ Ec,
    const float* __restrict__ bw2, const float* __restrict__ bc2,
    const float* __restrict__ cbw, const float* __restrict__ cbc,
    const float* __restrict__ Mw, const float* __restrict__ mbw,
    const float* __restrict__ Mc, const float* __restrict__ mbc,
    float4* __restrict__ base,
    const ushort_t* __restrict__ LwT, const ushort_t* __restrict__ phTb,
    ushort_t* __restrict__ Gt)
{
  // pool: conv branch uses 16x17 f32 (1.1KB); gemm branch stages 128x136 bf16 (34.8KB)
  __shared__ __align__(16) unsigned char smem[128*136*2];
  int bid = blockIdx.x, tid = threadIdx.x;
  if (bid < 256){
    // ---- fused conv-swish h + t-invariant MLP bases per (b,l) ----
    int b = bid >> 4, x = bid & 15;
    if (x >= 13){
      int l0 = 208 + (x - 13)*16;
      if (tid < 32)
        base[((size_t)(b*256 + l0 + (tid >> 1)))*2 + (tid & 1)] = make_float4(0,0,0,0);
      return;
    }
    float (*sh)[17] = (float (*)[17])smem;
    int lu = tid >> 4, u = tid & 15;
    int l = x*16 + lu;
    float h = 0.f;
    if (l < NL){
      int branch = u >> 3, oc = u & 7;
      const float* E  = branch ? Ec  : Ew;
      const float* b2 = branch ? bc2 : bw2;
      float val = (branch ? cbc : cbw)[oc];
      #pragma unroll
      for (int k = 0; k < 3; ++k){
        int ll = l + k - 1;
        if (ll < 0 || ll >= NL) continue;  // SAME zero-pad: drop term+bias
        float acc = b2[oc*3 + k];
        const float4* Er = (const float4*)(E + (oc*3 + k)*ND);
        const float4* pr = (const float4*)(phT + ((size_t)b*NL + ll)*ND);
        #pragma unroll 8
        for (int d = 0; d < 64; ++d){
          float4 e = Er[d], p = pr[d];
          acc += e.x*p.x + e.y*p.y + e.z*p.z + e.w*p.w;
        }
        val += acc;
      }
      float pm = (dur[b*NL + l] > 0.5f) ? 1.f : 0.f;
      h = silu_f(val) * pm;
    }
    sh[lu][u] = h;
    __syncthreads();
    if (tid < 16){
      int ll = x*16 + tid;
      float4 o0 = make_float4(0,0,0,0);
      float4 o1 = make_float4(0,0,0,0);
      if (ll < NL){
        float dl  = dur[b*NL + ll];
        float pm  = (dl > 0.5f) ? 1.f : 0.f;
        float skl = sk_ws[b*NL + ll];
        float c1[4], c2[2];
        #pragma unroll
        for (int q = 0; q < 4; ++q) c1[q] = mbw[q] + dl*Mw[4 + q] - skl*Mw[q];
        #pragma unroll
        for (int p = 0; p < 2; ++p) c2[p] = mbc[p] + dl*Mc[2 + p] - skl*Mc[p];
        #pragma unroll
        for (int j = 0; j < 8; ++j){
          float hwv = sh[tid][j], hcv = sh[tid][8 + j];
          #pragma unroll
          for (int q = 0; q < 4; ++q) c1[q] += hwv*Mw[(2 + j)*4 + q];
          #pragma unroll
          for (int p = 0; p < 2; ++p) c2[p] += hcv*Mc[(2 + j)*2 + p];
        }
        o0 = make_float4(c1[0], c1[1], c1[2], c1[3]);
        o1 = make_float4(c2[0], c2[1], pm, 0.f);
      }
      base[((size_t)(b*256 + ll))*2 + 0] = o0;
      base[((size_t)(b*256 + ll))*2 + 1] = o1;
    }
  } else {
    // ---- MFMA Gt = LwT x phTb^T, direct-register loads ----
    int r = bid - 256;                   // 256 = 2 x 2 x 64  (bq in [0,64))
    int xb = r & 1, yb = (r >> 1) & 1, bq = r >> 2;
    int b = bq >> 2, q = bq & 3;
    int m0 = yb * 128;                   // n dim
    int n0 = xb * 128;                   // l dim (padded)
    int lane = tid & 63, wave = tid >> 6;
    int wm = wave >> 1, wn = wave & 1;
    int col = lane & 15, kg4 = lane >> 4;
    f32x4 acc[4][4] = {};
    for (int kt = 0; kt < 8; ++kt){
      int k0 = kt*32;
      bf16x8 afr[4], bfr[4];
      #pragma unroll
      for (int i = 0; i < 4; ++i)
        afr[i] = *(const bf16x8*)(LwT + ((size_t)(q*256 + m0 + wm*64 + i*16 + col))*256 + k0 + kg4*8);
      #pragma unroll
      for (int j = 0; j < 4; ++j)
        bfr[j] = *(const bf16x8*)(phTb + ((size_t)(b*256 + n0 + wn*64 + j*16 + col))*256 + k0 + kg4*8);
      #pragma unroll
      for (int i = 0; i < 4; ++i)
        #pragma unroll
        for (int j = 0; j < 4; ++j)
          acc[i][j] = __builtin_amdgcn_mfma_f32_16x16x32_bf16(afr[i], bfr[j], acc[i][j], 0, 0, 0);
    }
    // ---- stage tile in LDS, then 16B-contiguous stores ----
    ushort_t (*st2)[136] = (ushort_t (*)[136])smem;
    int rq = lane >> 4;
    #pragma unroll
    for (int i = 0; i < 4; ++i){
      #pragma unroll
      for (int rr = 0; rr < 4; ++rr){
        int rl = wm*64 + i*16 + rq*4 + rr;
        #pragma unroll
        for (int j = 0; j < 4; ++j){
          int cl = wn*64 + j*16 + col;
          st2[rl][cl] = f2bf(acc[i][j][rr]);
        }
      }
    }
    __syncthreads();
    #pragma unroll
    for (int rep = 0; rep < 8; ++rep){
      int row = rep*16 + (tid >> 4);
      int ch  = tid & 15;
      int l   = n0 + ch*8;
      if (l < NL){
        int n = m0 + row;
        *(uint4*)(Gt + ((size_t)(b*ND + n))*800 + q*NL + l) = *(const uint4*)&st2[row][ch*8];
      }
    }
  }
}

// =========== K3: FUSED softmax + V-GEMM + out-GEMM per (b, 64-t tile) ==========
// TT=64, 1024 threads (16 waves), grid (16,16) = 256 blocks = exactly 1/CU.
// Pair-interleaved softmax, float4 wout stores, hoisted base loads.
#define AP 808
#define TT 64
__global__ __launch_bounds__(1024, 4) void k_wv_fused(
    const float4* __restrict__ base,
    const int* __restrict__ fl_ws,
    const float* __restrict__ Mw, const float* __restrict__ Mc,
    const ushort_t* __restrict__ Gt,    // [16][256][800] bf16
    const float* __restrict__ Lc,       // [8][256]
    const float* __restrict__ lbc,      // [256]
    const float* __restrict__ lbw,      // [256]
    const ushort_t* __restrict__ WoT,   // [512][256] bf16
    const float* __restrict__ bo,       // [512]
    float* __restrict__ wout,
    float* __restrict__ o_mean, float* __restrict__ o_lstd)
{
  __shared__ ushort_t As[TT*AP];   // 103.4 KB w-tile [t_local][k=q*200+l]
  __shared__ float    wcs[TT][8];  // 2 KB per-t wc
  int b = blockIdx.x;              // batch -> XCD = b%8
  int m0 = blockIdx.y * TT;        // t tile (16 tiles cover 0..1023)
  int tid = threadIdx.x, lane = tid & 63, wave = tid >> 6;   // 16 waves
  int col = lane & 15, kg4 = lane >> 4;
  int fl = fl_ws[b];

  // ---------------- early-out: fully-masked tile ----------------
  if (fl <= m0){
    for (int idx = tid; idx < TT*4*50; idx += 1024){
      int tl = idx / 200;
      int rqs = idx - tl*200;
      int q = rqs / 50, seg = rqs - q*50;
      int t = m0 + tl;
      if (t < NT)
        *(float4*)&wout[(((size_t)(b*4 + q))*NT + t)*NL + seg*4] = make_float4(0,0,0,0);
    }
    for (int idx = tid; idx < 512*16; idx += 1024){
      int s = idx >> 4, j = idx & 15;
      int t0 = m0 + j*4;
      if (t0 + 3 < NT){
        float v = bo[s];
        float4 v4 = make_float4(v, v, v, v);
        if (s < ND) *(float4*)&o_mean[((size_t)b*ND + s)*NT + t0] = v4;
        else        *(float4*)&o_lstd[((size_t)b*ND + (s - ND))*NT + t0] = v4;
      }
    }
    return;
  }

  // ---------------- phase 1: softmax, lane owns l = lane*4..lane*4+3 ----------
  int l0 = lane*4;
  bool lv = (l0 < NL);             // lanes 0..49 active

  #pragma unroll
  for (int s = 0; s < 4; ++s){
    int tl = wave*4 + s, t = m0 + tl;
    if (t < fl) continue;
    for (int k = l0; k < 800; k += 256){
      uint2 zz2; zz2.x = 0u; zz2.y = 0u;
      *(uint2*)&As[tl*AP + k] = zz2;
    }
    if (lane < 8) wcs[tl][lane] = 0.f;
    if (t < NT && lv){
      float4 z4 = make_float4(0,0,0,0);
      #pragma unroll
      for (int q = 0; q < 4; ++q)
        *(float4*)&wout[(((size_t)(b*4 + q))*NT + t)*NL + l0] = z4;
    }
  }

  float b0a[4][4], b1x[4], b1y[4], pmv[4];
  #pragma unroll
  for (int e = 0; e < 4; ++e){
    float4 v0 = make_float4(0,0,0,0), v1 = make_float4(0,0,0,0);
    if (lv){
      v0 = base[((size_t)(b*256 + l0 + e))*2 + 0];
      v1 = base[((size_t)(b*256 + l0 + e))*2 + 1];
    }
    b0a[e][0] = v0.x; b0a[e][1] = v0.y; b0a[e][2] = v0.z; b0a[e][3] = v0.w;
    b1x[e] = v1.x; b1y[e] = v1.y; pmv[e] = v1.z;
  }
  float mwq[4] = {Mw[0], Mw[1], Mw[2], Mw[3]};
  float mcp[2] = {Mc[0], Mc[1]};

  for (int sp = 0; sp < 2; ++sp){
    int tl0 = wave*4 + sp*2;
    int t0 = m0 + tl0;
    if (t0 >= fl) break;
    bool a1 = (t0 + 1 < fl);
    float tf[2] = {(float)(t0 + 1), (float)(t0 + 2)};

    float z[2][4][4], mx[2][4];
    #pragma unroll
    for (int u = 0; u < 2; ++u)
      #pragma unroll
      for (int q = 0; q < 4; ++q) mx[u][q] = -INFINITY;
    #pragma unroll
    for (int e = 0; e < 4; ++e){
      #pragma unroll
      for (int u = 0; u < 2; ++u){
        #pragma unroll
        for (int q = 0; q < 4; ++q){
          float sv = silu_f(b0a[e][q] + tf[u]*mwq[q]);
          float zv = (pmv[e] > 0.f) ? sv : -INFINITY;
          z[u][e][q] = zv;
          mx[u][q] = fmaxf(mx[u][q], zv);
        }
      }
    }
    #pragma unroll
    for (int u = 0; u < 2; ++u)
      #pragma unroll
      for (int q = 0; q < 4; ++q){
        float v = mx[u][q];
        #pragma unroll
        for (int off = 32; off; off >>= 1) v = fmaxf(v, __shfl_xor(v, off));
        mx[u][q] = v;
      }
    float is4[2][4] = {{0,0,0,0},{0,0,0,0}};
    #pragma unroll
    for (int e = 0; e < 4; ++e){
      #pragma unroll
      for (int u = 0; u < 2; ++u){
        #pragma unroll
        for (int q = 0; q < 4; ++q){
          float ev = (pmv[e] > 0.f) ? __expf(z[u][e][q] - mx[u][q]) : 0.f;
          z[u][e][q] = ev;
          is4[u][q] += ev;
        }
      }
    }
    #pragma unroll
    for (int u = 0; u < 2; ++u)
      #pragma unroll
      for (int q = 0; q < 4; ++q){
        float v = is4[u][q];
        #pragma unroll
        for (int off = 32; off; off >>= 1) v += __shfl_xor(v, off);
        is4[u][q] = 1.f / v;
      }
    float cv[2][4][2];
    #pragma unroll
    for (int e = 0; e < 4; ++e)
      #pragma unroll
      for (int u = 0; u < 2; ++u){
        cv[u][e][0] = silu_f(b1x[e] + tf[u]*mcp[0]);
        cv[u][e][1] = silu_f(b1y[e] + tf[u]*mcp[1]);
      }
    float wc[2][8];
    #pragma unroll
    for (int u = 0; u < 2; ++u)
      #pragma unroll
      for (int x = 0; x < 8; ++x) wc[u][x] = 0.f;
    #pragma unroll
    for (int u = 0; u < 2; ++u){
      bool act = (u == 0) || a1;
      int t = t0 + u, tl = tl0 + u;
      #pragma unroll
      for (int q = 0; q < 4; ++q){
        float w0 = z[u][0][q]*is4[u][q];
        float w1 = z[u][1][q]*is4[u][q];
        float w2 = z[u][2][q]*is4[u][q];
        float w3 = z[u][3][q]*is4[u][q];
        if (act && lv){
          *(float4*)&wout[(((size_t)(b*4 + q))*NT + t)*NL + l0] =
              make_float4(w0, w1, w2, w3);
          uint2 pk;
          pk.x = (unsigned)f2bf(w0) | ((unsigned)f2bf(w1) << 16);
          pk.y = (unsigned)f2bf(w2) | ((unsigned)f2bf(w3) << 16);
          *(uint2*)&As[tl*AP + q*NL + l0] = pk;
        }
        wc[u][q*2 + 0] += w0*cv[u][0][0] + w1*cv[u][1][0] + w2*cv[u][2][0] + w3*cv[u][3][0];
        wc[u][q*2 + 1] += w0*cv[u][0][1] + w1*cv[u][1][1] + w2*cv[u][2][1] + w3*cv[u][3][1];
      }
    }
    #pragma unroll
    for (int u = 0; u < 2; ++u){
      if (u == 1 && !a1) break;
      #pragma unroll
      for (int x = 0; x < 8; ++x){
        float v = wc[u][x];
        #pragma unroll
        for (int off = 32; off; off >>= 1) v += __shfl_xor(v, off);
        wc[u][x] = v;
      }
      if (lane == 0){
        #pragma unroll
        for (int x = 0; x < 8; ++x) wcs[tl0 + u][x] = wc[u][x];
      }
    }
  }
  __syncthreads();

  // ------- phase 2: MFMA over K=800; each wave owns 16 Gt rows, 4 t-tiles -----
  f32x4 acc[4] = {};
  const ushort_t* Gb = Gt + (size_t)b*ND*800;
  for (int kt = 0; kt < 25; ++kt){
    int k0 = kt*32;
    bf16x8 afr[4], bfr;
    #pragma unroll
    for (int i = 0; i < 4; ++i)
      afr[i] = *(const bf16x8*)(&As[(i*16 + col)*AP + k0 + kg4*8]);
    bfr = *(const bf16x8*)(Gb + ((size_t)(wave*16 + col))*800 + k0 + kg4*8);
    #pragma unroll
    for (int i = 0; i < 4; ++i)
      acc[i] = __builtin_amdgcn_mfma_f32_16x16x32_bf16(afr[i], bfr, acc[i], 0, 0, 0);
  }
  __syncthreads();   // all waves done reading As -> safe to reuse as whc tile

  // ---- epilogue: whc[t][n] = fm*(vh + lbw + (lbc + wc.Lc)) -> LDS (stc) ----
  ushort_t (*stc)[264] = (ushort_t (*)[264])As;   // 64 x 264 bf16 (33.8KB)
  {
    int rq = lane >> 4;
    int n = wave*16 + col;
    float lbn = lbc[n], lbwn = lbw[n];
    float lcn[8];
    #pragma unroll
    for (int u = 0; u < 8; ++u) lcn[u] = Lc[u*ND + n];
    #pragma unroll
    for (int i = 0; i < 4; ++i){
      #pragma unroll
      for (int r = 0; r < 4; ++r){
        int tl = i*16 + rq*4 + r;
        int t = m0 + tl;
        if (t < NT){
          float f = (t < fl) ? 1.f : 0.f;
          float vcv = lbn
            + wcs[tl][0]*lcn[0] + wcs[tl][1]*lcn[1]
            + wcs[tl][2]*lcn[2] + wcs[tl][3]*lcn[3]
            + wcs[tl][4]*lcn[4] + wcs[tl][5]*lcn[5]
            + wcs[tl][6]*lcn[6] + wcs[tl][7]*lcn[7];
          stc[tl][n] = f2bf(f * (acc[i][r] + lbwn + vcv));
        }
      }
    }
  }
  __syncthreads();   // stc tile complete

  // -------- phase 3: out = WoT x stc^T (512 x 64 per block), from LDS --------
  {
    f32x4 acc2[2][4] = {};
    for (int kt = 0; kt < 8; ++kt){
      int k0 = kt*32;
      bf16x8 afr[2], bfr[4];
      #pragma unroll
      for (int j = 0; j < 4; ++j)
        bfr[j] = *(const bf16x8*)(&stc[j*16 + col][k0 + kg4*8]);
      #pragma unroll
      for (int i = 0; i < 2; ++i)
        afr[i] = *(const bf16x8*)(WoT + ((size_t)(wave*32 + i*16 + col))*ND + k0 + kg4*8);
      #pragma unroll
      for (int i = 0; i < 2; ++i)
        #pragma unroll
        for (int j = 0; j < 4; ++j)
          acc2[i][j] = __builtin_amdgcn_mfma_f32_16x16x32_bf16(afr[i], bfr[j], acc2[i][j], 0, 0, 0);
    }
    int rq = lane >> 4;
    #pragma unroll
    for (int i = 0; i < 2; ++i){
      #pragma unroll
      for (int r = 0; r < 4; ++r){
        int s = wave*32 + i*16 + rq*4 + r;
        float bov = bo[s];
        #pragma unroll
        for (int j = 0; j < 4; ++j){
          int t = m0 + j*16 + col;
          if (t < NT){
            float v = acc2[i][j][r] + bov;
            if (s < ND) o_mean[((size_t)b*ND + s)*NT + t] = v;
            else        o_lstd[((size_t)b*ND + (s - ND))*NT + t] = v;
          }
        }
      }
    }
  }
}

extern "C" void kernel_launch(void* const* d_in, const int* in_sizes, int n_in,
                              void* d_out, int out_size, void* d_ws, size_t ws_size,
                              hipStream_t stream)
{
  const float* dur = (const float*)d_in[0];
  const float* ph  = (const float*)d_in[1];
  // d_in[2] phoneme_mask: unused (pm == durations > 0)
  const float* Wpw = (const float*)d_in[3];
  const float* bpw = (const float*)d_in[4];
  const float* Cw  = (const float*)d_in[5];
  const float* cbw = (const float*)d_in[6];
  const float* Mw  = (const float*)d_in[7];
  const float* mbw = (const float*)d_in[8];
  const float* Lw  = (const float*)d_in[9];
  const float* lbw = (const float*)d_in[10];
  const float* Wpc = (const float*)d_in[11];
  const float* bpc = (const float*)d_in[12];
  const float* Cc  = (const float*)d_in[13];
  const float* cbc = (const float*)d_in[14];
  const float* Mc  = (const float*)d_in[15];
  const float* mbc = (const float*)d_in[16];
  const float* Lc  = (const float*)d_in[17];
  const float* lbc = (const float*)d_in[18];
  const float* Wo  = (const float*)d_in[19];
  const float* bo  = (const float*)d_in[20];

  float* out    = (float*)d_out;
  float* o_mean = out;
  float* o_lstd = out + (size_t)NB*ND*NT;
  float* o_fm   = o_lstd + (size_t)NB*ND*NT;
  float* o_fl   = o_fm + NB*NT;
  float* o_w    = o_fl + NB;

  float* ws   = (float*)d_ws;
  float* phT  = ws + OFF_PHT;
  float* sk   = ws + OFF_SK;
  float* Ew   = ws + OFF_EW;
  float* Ec   = ws + OFF_EC;
  float* bw2  = ws + OFF_BW2;
  float* bc2  = ws + OFF_BC2;
  int*   fl   = (int*)(ws + OFF_FL);
  ushort_t* Gt   = (ushort_t*)(ws + OFF_GT);
  ushort_t* WoT  = (ushort_t*)(ws + OFF_WOT);
  float4*   base = (float4*)(ws + OFF_BASE);
  ushort_t* phTb = (ushort_t*)(ws + OFF_PHTB);
  ushort_t* LwT  = (ushort_t*)(ws + OFF_LWT);

  k_stage1<<<2624, 256, 0, stream>>>(dur, ph, Wpw, Cw, bpw, Wpc, Cc, bpc, Wo, Lw,
                                     sk, fl, o_fm, o_fl, Ew, Ec, bw2, bc2,
                                     WoT, LwT, phT, phTb);
  k_stage2<<<512, 256, 0, stream>>>(phT, dur, sk, Ew, Ec, bw2, bc2, cbw, cbc,
                                    Mw, mbw, Mc, mbc, base, LwT, phTb, Gt);
  {
    dim3 g(NB, 16);   // flat id = b + 16*ttile  ->  XCD(id%8) = b%8
    k_wv_fused<<<g, 1024, 0, stream>>>(base, fl, Mw, Mc, Gt, Lc, lbc, lbw,
                                       WoT, bo, o_w, o_mean, o_lstd);
  }
}

// Round 15
// 226.237 us; speedup vs baseline: 1.1339x; 1.0567x over previous
//
#include <hip/hip_runtime.h>
#include <hip/hip_bf16.h>
#include <math.h>

#define NB 16
#define ND 256
#define NL 200
#define NT 1000

typedef unsigned short ushort_t;
typedef __bf16 bf16x8 __attribute__((ext_vector_type(8)));
typedef float f32x4 __attribute__((ext_vector_type(4)));

// ---- workspace layout (float offsets) ----
#define OFF_EW    4969600u   // E[oc][k][d]                  6144
#define OFF_EC    4975744u   //                              6144
#define OFF_BW2   4981888u   //                              24
#define OFF_BC2   4981912u   //                              24
#define OFF_FL    4981936u   // frame_lengths int            16
#define OFF_GT    11535552u  // Gt bf16 [b][256][800]        1638400 floats
#define OFF_WOT   15221952u  // WoT bf16 [512][256]          65536 floats
#define OFF_BASE  15287488u  // base[b][256][8] fp32         32768 floats

__device__ __forceinline__ float silu_f(float x){ return x / (1.f + __expf(-x)); }
__device__ __forceinline__ ushort_t f2bf(float x){
  __hip_bfloat16 h = __float2bfloat16(x);
  return *(ushort_t*)&h;
}

// =========== STAGE 1': prep(16) | E-fold(48) = 64 blocks only ==================
// Everything else (transpose, packs) moved into self-sufficient stage 2.
__global__ __launch_bounds__(256) void k_stage1(
    const float* __restrict__ dur,
    const float* __restrict__ Wp_w, const float* __restrict__ C_w, const float* __restrict__ bp_w,
    const float* __restrict__ Wp_c, const float* __restrict__ C_c, const float* __restrict__ bp_c,
    int* __restrict__ fl_ws, float* __restrict__ o_fm, float* __restrict__ o_fl,
    float* __restrict__ Ew, float* __restrict__ Ec,
    float* __restrict__ bw2, float* __restrict__ bc2)
{
  int bid = blockIdx.x, tid = threadIdx.x;
  if (bid < 16){
    // ---- prep: frame_lengths, frame_mask ----
    int b = bid;
    __shared__ float sdur[NL];
    __shared__ int sfl;
    if (tid < NL) sdur[tid] = dur[b*NL + tid];
    __syncthreads();
    if (tid == 0){
      float run = 0.f;
      for (int l = 0; l < NL; ++l) run += sdur[l];
      int fl = (int)rintf(run);          // round-half-even, matches jnp.round
      fl = fl < 0 ? 0 : (fl > NT ? NT : fl);
      sfl = fl; fl_ws[b] = fl; o_fl[b] = (float)fl;
    }
    __syncthreads();
    for (int t = tid; t < NT; t += 256) o_fm[b*NT + t] = (t < sfl) ? 1.f : 0.f;
  } else {
    // ---- E-fold: E[oc][k][d] = sum_i C[oc][i][k] * Wp[i][d]  (+bias fold) ----
    int sbid = bid - 16;                 // [0,48)
    int gid = sbid*256 + tid;            // 12288 = 2 * 8*3*256
    int branch = gid / 6144;
    int r = gid % 6144;
    int d = r & 255;
    int ock = r >> 8;                    // oc*3+k
    int oc = ock / 3, k = ock % 3;
    const float* Wp = branch ? Wp_c : Wp_w;
    const float* C  = branch ? C_c  : C_w;
    float acc = 0.f;
    for (int i = 0; i < ND; ++i) acc += C[(oc*ND + i)*3 + k] * Wp[i*ND + d];
    (branch ? Ec : Ew)[r] = acc;
    if (d == 0){
      const float* bp = branch ? bp_c : bp_w;
      float bb = 0.f;
      for (int i = 0; i < ND; ++i) bb += C[(oc*ND + i)*3 + k] * bp[i];
      (branch ? bc2 : bw2)[ock] = bb;
    }
  }
}

// =========== STAGE 2': conv+base(256) | gemmG(256) | WoTpack(128) = 640 blocks =
// Self-sufficient from inputs + E: conv self-transposes its ph slice and
// self-computes the dur cumsum (identical serial order); gemmG self-stages
// Lw/ph coalesced as bf16 (same f2bf values, same ascending-k accumulation).
__global__ __launch_bounds__(256, 4) void k_stage2(
    const float* __restrict__ dur, const float* __restrict__ ph,
    const float* __restrict__ Ew, const float* __restrict__ Ec,
    const float* __restrict__ bw2, const float* __restrict__ bc2,
    const float* __restrict__ cbw, const float* __restrict__ cbc,
    const float* __restrict__ Mw, const float* __restrict__ mbw,
    const float* __restrict__ Mc, const float* __restrict__ mbc,
    const float* __restrict__ Lw, const float* __restrict__ Wo,
    float4* __restrict__ base, ushort_t* __restrict__ Gt,
    ushort_t* __restrict__ WoT)
{
  __shared__ __align__(16) unsigned char smem[36864];
  int bid = blockIdx.x, tid = threadIdx.x;

  if (bid < 256){
    // ---- conv-with-E + base, self-sufficient ----
    int b = bid >> 4, x = bid & 15;
    if (x >= 13){
      int l0 = 208 + (x - 13)*16;
      if (tid < 32)
        base[((size_t)(b*256 + l0 + (tid >> 1)))*2 + (tid & 1)] = make_float4(0,0,0,0);
      return;
    }
    float* phs  = (float*)smem;                    // [18][256] 18432 B
    float* sdur = (float*)(smem + 18432);          // 256 f
    float* ssk  = (float*)(smem + 19456);          // 256 f
    float (*sh)[17] = (float (*)[17])(smem + 20480); // 16 x 17
    int l0 = x*16;

    if (tid < NL) sdur[tid] = dur[b*NL + tid];
    __syncthreads();
    if (tid == 0){
      float run = 0.f;
      for (int l = 0; l < NL; ++l){ ssk[l] = run; run += sdur[l]; }
    }
    // stage ph slice: phs[j][d] <- ph[b][d][l0-1+j] (coalesced per j across d)
    {
      const float* pr = ph + ((size_t)b*ND + tid)*NL;
      #pragma unroll
      for (int j = 0; j < 18; ++j){
        int l = l0 - 1 + j;
        phs[j*256 + tid] = (l >= 0 && l < NL) ? pr[l] : 0.f;
      }
    }
    __syncthreads();
    // conv-with-E (identical math/order to the verified stage2)
    {
      int lu = tid >> 4, u = tid & 15;
      int l = l0 + lu;
      float h = 0.f;
      if (l < NL){
        int branch = u >> 3, oc = u & 7;
        const float* E  = branch ? Ec  : Ew;
        const float* b2 = branch ? bc2 : bw2;
        float val = (branch ? cbc : cbw)[oc];
        #pragma unroll
        for (int k = 0; k < 3; ++k){
          int ll = l + k - 1;
          if (ll < 0 || ll >= NL) continue;  // SAME zero-pad: drop term+bias
          float acc = b2[oc*3 + k];
          const float4* Er = (const float4*)(E + (oc*3 + k)*ND);
          const float4* pr = (const float4*)&phs[(lu + k)*256];
          #pragma unroll 8
          for (int d = 0; d < 64; ++d){
            float4 e = Er[d], p = pr[d];
            acc += e.x*p.x + e.y*p.y + e.z*p.z + e.w*p.w;
          }
          val += acc;
        }
        float pm = (sdur[l] > 0.5f) ? 1.f : 0.f;
        h = silu_f(val) * pm;
      }
      sh[lu][u] = h;
    }
    __syncthreads();
    // base/MLP epilogue (identical math)
    if (tid < 16){
      int ll = x*16 + tid;
      float4 o0 = make_float4(0,0,0,0);
      float4 o1 = make_float4(0,0,0,0);
      if (ll < NL){
        float dl  = sdur[ll];
        float pm  = (dl > 0.5f) ? 1.f : 0.f;
        float skl = ssk[ll];
        float c1[4], c2[2];
        #pragma unroll
        for (int q = 0; q < 4; ++q) c1[q] = mbw[q] + dl*Mw[4 + q] - skl*Mw[q];
        #pragma unroll
        for (int p = 0; p < 2; ++p) c2[p] = mbc[p] + dl*Mc[2 + p] - skl*Mc[p];
        #pragma unroll
        for (int j = 0; j < 8; ++j){
          float hwv = sh[tid][j], hcv = sh[tid][8 + j];
          #pragma unroll
          for (int q = 0; q < 4; ++q) c1[q] += hwv*Mw[(2 + j)*4 + q];
          #pragma unroll
          for (int p = 0; p < 2; ++p) c2[p] += hcv*Mc[(2 + j)*2 + p];
        }
        o0 = make_float4(c1[0], c1[1], c1[2], c1[3]);
        o1 = make_float4(c2[0], c2[1], pm, 0.f);
      }
      base[((size_t)(b*256 + ll))*2 + 0] = o0;
      base[((size_t)(b*256 + ll))*2 + 1] = o1;
    }
  } else if (bid < 512){
    // ---- Gt = Lw x ph (per b,q), coalesced quarter-K self-staging ----
    int r = bid - 256;                   // (xb, yb, b, q)
    int xb = r & 1, yb = (r >> 1) & 1, bq = r >> 2;
    int b = bq >> 2, q = bq & 3;
    int m0 = yb * 128;                   // n dim
    int n0 = xb * 128;                   // l dim
    int lane = tid & 63, wave = tid >> 6;
    int wm = wave >> 1, wn = wave & 1;
    int col = lane & 15, kg4 = lane >> 4;
    ushort_t (*Asub)[72] = (ushort_t (*)[72])smem;             // 18432 B
    ushort_t (*Bsub)[72] = (ushort_t (*)[72])(smem + 18432);   // 18432 B
    int na = lane*2;                     // n-pair this lane owns

    f32x4 acc[4][4] = {};
    for (int kq = 0; kq < 4; ++kq){
      int d0 = kq*64;
      for (int rep = 0; rep < 16; ++rep){
        int dk = wave*16 + rep;
        float2 v = *(const float2*)(Lw + ((size_t)(q*256 + d0 + dk))*ND + m0 + na);
        Asub[na    ][dk] = f2bf(v.x);
        Asub[na + 1][dk] = f2bf(v.y);
      }
      for (int rep = 0; rep < 16; ++rep){
        int dk = wave*16 + rep;
        int l = n0 + na;
        float2 v; v.x = 0.f; v.y = 0.f;
        if (l < NL)
          v = *(const float2*)(ph + ((size_t)b*ND + d0 + dk)*NL + l);
        Bsub[na    ][dk] = f2bf(v.x);
        Bsub[na + 1][dk] = f2bf(v.y);
      }
      __syncthreads();
      for (int kt = 0; kt < 2; ++kt){
        int k0 = kt*32;
        bf16x8 afr[4], bfr[4];
        #pragma unroll
        for (int i = 0; i < 4; ++i)
          afr[i] = *(const bf16x8*)&Asub[wm*64 + i*16 + col][k0 + kg4*8];
        #pragma unroll
        for (int j = 0; j < 4; ++j)
          bfr[j] = *(const bf16x8*)&Bsub[wn*64 + j*16 + col][k0 + kg4*8];
        #pragma unroll
        for (int i = 0; i < 4; ++i)
          #pragma unroll
          for (int j = 0; j < 4; ++j)
            acc[i][j] = __builtin_amdgcn_mfma_f32_16x16x32_bf16(afr[i], bfr[j], acc[i][j], 0, 0, 0);
      }
      __syncthreads();
    }
    // stage output tile (overlays Asub+Bsub), coalesced 16B stores
    ushort_t (*st2)[136] = (ushort_t (*)[136])smem;            // 34816 B
    int rq = lane >> 4;
    #pragma unroll
    for (int i = 0; i < 4; ++i){
      #pragma unroll
      for (int rr = 0; rr < 4; ++rr){
        int rl = wm*64 + i*16 + rq*4 + rr;
        #pragma unroll
        for (int j = 0; j < 4; ++j){
          int cl = wn*64 + j*16 + col;
          st2[rl][cl] = f2bf(acc[i][j][rr]);
        }
      }
    }
    __syncthreads();
    #pragma unroll
    for (int rep = 0; rep < 8; ++rep){
      int row = rep*16 + (tid >> 4);
      int ch  = tid & 15;
      int l   = n0 + ch*8;
      if (l < NL){
        int n = m0 + row;
        *(uint4*)(Gt + ((size_t)(b*ND + n))*800 + q*NL + l) = *(const uint4*)&st2[row][ch*8];
      }
    }
  } else {
    // ---- WoT pack: WoT[n][k] = Wo[k][n] bf16 ----
    int base_id = (bid - 512)*256 + tid;
    #pragma unroll
    for (int rep = 0; rep < 4; ++rep){
      int gid = rep*32768 + base_id;     // 131072 total
      int n = gid >> 8, k = gid & 255;
      WoT[gid] = f2bf(Wo[(size_t)k*512 + n]);
    }
  }
}

// =========== K3: FUSED softmax + V-GEMM + out-GEMM per (b, 64-t tile) ==========
// TT=64, 1024 threads (16 waves), grid (16,16) = 256 blocks = exactly 1/CU.
// (R7/R14 verbatim — measured best, wv restructuring closed.)
#define AP 808
#define TT 64
__global__ __launch_bounds__(1024, 4) void k_wv_fused(
    const float4* __restrict__ base,
    const int* __restrict__ fl_ws,
    const float* __restrict__ Mw, const float* __restrict__ Mc,
    const ushort_t* __restrict__ Gt,    // [16][256][800] bf16
    const float* __restrict__ Lc,       // [8][256]
    const float* __restrict__ lbc,      // [256]
    const float* __restrict__ lbw,      // [256]
    const ushort_t* __restrict__ WoT,   // [512][256] bf16
    const float* __restrict__ bo,       // [512]
    float* __restrict__ wout,
    float* __restrict__ o_mean, float* __restrict__ o_lstd)
{
  __shared__ ushort_t As[TT*AP];   // 103.4 KB w-tile [t_local][k=q*200+l]
  __shared__ float    wcs[TT][8];  // 2 KB per-t wc
  int b = blockIdx.x;              // batch -> XCD = b%8
  int m0 = blockIdx.y * TT;        // t tile (16 tiles cover 0..1023)
  int tid = threadIdx.x, lane = tid & 63, wave = tid >> 6;   // 16 waves
  int col = lane & 15, kg4 = lane >> 4;
  int fl = fl_ws[b];

  // ---------------- early-out: fully-masked tile ----------------
  if (fl <= m0){
    for (int idx = tid; idx < TT*4*50; idx += 1024){
      int tl = idx / 200;
      int rqs = idx - tl*200;
      int q = rqs / 50, seg = rqs - q*50;
      int t = m0 + tl;
      if (t < NT)
        *(float4*)&wout[(((size_t)(b*4 + q))*NT + t)*NL + seg*4] = make_float4(0,0,0,0);
    }
    for (int idx = tid; idx < 512*16; idx += 1024){
      int s = idx >> 4, j = idx & 15;
      int t0 = m0 + j*4;
      if (t0 + 3 < NT){
        float v = bo[s];
        float4 v4 = make_float4(v, v, v, v);
        if (s < ND) *(float4*)&o_mean[((size_t)b*ND + s)*NT + t0] = v4;
        else        *(float4*)&o_lstd[((size_t)b*ND + (s - ND))*NT + t0] = v4;
      }
    }
    return;
  }

  // ---------------- phase 1: softmax, lane owns l = lane*4..lane*4+3 ----------
  int l0 = lane*4;
  bool lv = (l0 < NL);             // lanes 0..49 active

  #pragma unroll
  for (int s = 0; s < 4; ++s){
    int tl = wave*4 + s, t = m0 + tl;
    if (t < fl) continue;
    for (int k = l0; k < 800; k += 256){
      uint2 zz2; zz2.x = 0u; zz2.y = 0u;
      *(uint2*)&As[tl*AP + k] = zz2;
    }
    if (lane < 8) wcs[tl][lane] = 0.f;
    if (t < NT && lv){
      float4 z4 = make_float4(0,0,0,0);
      #pragma unroll
      for (int q = 0; q < 4; ++q)
        *(float4*)&wout[(((size_t)(b*4 + q))*NT + t)*NL + l0] = z4;
    }
  }

  float b0a[4][4], b1x[4], b1y[4], pmv[4];
  #pragma unroll
  for (int e = 0; e < 4; ++e){
    float4 v0 = make_float4(0,0,0,0), v1 = make_float4(0,0,0,0);
    if (lv){
      v0 = base[((size_t)(b*256 + l0 + e))*2 + 0];
      v1 = base[((size_t)(b*256 + l0 + e))*2 + 1];
    }
    b0a[e][0] = v0.x; b0a[e][1] = v0.y; b0a[e][2] = v0.z; b0a[e][3] = v0.w;
    b1x[e] = v1.x; b1y[e] = v1.y; pmv[e] = v1.z;
  }
  float mwq[4] = {Mw[0], Mw[1], Mw[2], Mw[3]};
  float mcp[2] = {Mc[0], Mc[1]};

  for (int sp = 0; sp < 2; ++sp){
    int tl0 = wave*4 + sp*2;
    int t0 = m0 + tl0;
    if (t0 >= fl) break;
    bool a1 = (t0 + 1 < fl);
    float tf[2] = {(float)(t0 + 1), (float)(t0 + 2)};

    float z[2][4][4], mx[2][4];
    #pragma unroll
    for (int u = 0; u < 2; ++u)
      #pragma unroll
      for (int q = 0; q < 4; ++q) mx[u][q] = -INFINITY;
    #pragma unroll
    for (int e = 0; e < 4; ++e){
      #pragma unroll
      for (int u = 0; u < 2; ++u){
        #pragma unroll
        for (int q = 0; q < 4; ++q){
          float sv = silu_f(b0a[e][q] + tf[u]*mwq[q]);
          float zv = (pmv[e] > 0.f) ? sv : -INFINITY;
          z[u][e][q] = zv;
          mx[u][q] = fmaxf(mx[u][q], zv);
        }
      }
    }
    #pragma unroll
    for (int u = 0; u < 2; ++u)
      #pragma unroll
      for (int q = 0; q < 4; ++q){
        float v = mx[u][q];
        #pragma unroll
        for (int off = 32; off; off >>= 1) v = fmaxf(v, __shfl_xor(v, off));
        mx[u][q] = v;
      }
    float is4[2][4] = {{0,0,0,0},{0,0,0,0}};
    #pragma unroll
    for (int e = 0; e < 4; ++e){
      #pragma unroll
      for (int u = 0; u < 2; ++u){
        #pragma unroll
        for (int q = 0; q < 4; ++q){
          float ev = (pmv[e] > 0.f) ? __expf(z[u][e][q] - mx[u][q]) : 0.f;
          z[u][e][q] = ev;
          is4[u][q] += ev;
        }
      }
    }
    #pragma unroll
    for (int u = 0; u < 2; ++u)
      #pragma unroll
      for (int q = 0; q < 4; ++q){
        float v = is4[u][q];
        #pragma unroll
        for (int off = 32; off; off >>= 1) v += __shfl_xor(v, off);
        is4[u][q] = 1.f / v;
      }
    float cv[2][4][2];
    #pragma unroll
    for (int e = 0; e < 4; ++e)
      #pragma unroll
      for (int u = 0; u < 2; ++u){
        cv[u][e][0] = silu_f(b1x[e] + tf[u]*mcp[0]);
        cv[u][e][1] = silu_f(b1y[e] + tf[u]*mcp[1]);
      }
    float wc[2][8];
    #pragma unroll
    for (int u = 0; u < 2; ++u)
      #pragma unroll
      for (int x = 0; x < 8; ++x) wc[u][x] = 0.f;
    #pragma unroll
    for (int u = 0; u < 2; ++u){
      bool act = (u == 0) || a1;
      int t = t0 + u, tl = tl0 + u;
      #pragma unroll
      for (int q = 0; q < 4; ++q){
        float w0 = z[u][0][q]*is4[u][q];
        float w1 = z[u][1][q]*is4[u][q];
        float w2 = z[u][2][q]*is4[u][q];
        float w3 = z[u][3][q]*is4[u][q];
        if (act && lv){
          *(float4*)&wout[(((size_t)(b*4 + q))*NT + t)*NL + l0] =
              make_float4(w0, w1, w2, w3);
          uint2 pk;
          pk.x = (unsigned)f2bf(w0) | ((unsigned)f2bf(w1) << 16);
          pk.y = (unsigned)f2bf(w2) | ((unsigned)f2bf(w3) << 16);
          *(uint2*)&As[tl*AP + q*NL + l0] = pk;
        }
        wc[u][q*2 + 0] += w0*cv[u][0][0] + w1*cv[u][1][0] + w2*cv[u][2][0] + w3*cv[u][3][0];
        wc[u][q*2 + 1] += w0*cv[u][0][1] + w1*cv[u][1][1] + w2*cv[u][2][1] + w3*cv[u][3][1];
      }
    }
    #pragma unroll
    for (int u = 0; u < 2; ++u){
      if (u == 1 && !a1) break;
      #pragma unroll
      for (int x = 0; x < 8; ++x){
        float v = wc[u][x];
        #pragma unroll
        for (int off = 32; off; off >>= 1) v += __shfl_xor(v, off);
        wc[u][x] = v;
      }
      if (lane == 0){
        #pragma unroll
        for (int x = 0; x < 8; ++x) wcs[tl0 + u][x] = wc[u][x];
      }
    }
  }
  __syncthreads();

  // ------- phase 2: MFMA over K=800; each wave owns 16 Gt rows, 4 t-tiles -----
  f32x4 acc[4] = {};
  const ushort_t* Gb = Gt + (size_t)b*ND*800;
  for (int kt = 0; kt < 25; ++kt){
    int k0 = kt*32;
    bf16x8 afr[4], bfr;
    #pragma unroll
    for (int i = 0; i < 4; ++i)
      afr[i] = *(const bf16x8*)(&As[(i*16 + col)*AP + k0 + kg4*8]);
    bfr = *(const bf16x8*)(Gb + ((size_t)(wave*16 + col))*800 + k0 + kg4*8);
    #pragma unroll
    for (int i = 0; i < 4; ++i)
      acc[i] = __builtin_amdgcn_mfma_f32_16x16x32_bf16(afr[i], bfr, acc[i], 0, 0, 0);
  }
  __syncthreads();   // all waves done reading As -> safe to reuse as whc tile

  // ---- epilogue: whc[t][n] = fm*(vh + lbw + (lbc + wc.Lc)) -> LDS (stc) ----
  ushort_t (*stc)[264] = (ushort_t (*)[264])As;   // 64 x 264 bf16 (33.8KB)
  {
    int rq = lane >> 4;
    int n = wave*16 + col;
    float lbn = lbc[n], lbwn = lbw[n];
    float lcn[8];
    #pragma unroll
    for (int u = 0; u < 8; ++u) lcn[u] = Lc[u*ND + n];
    #pragma unroll
    for (int i = 0; i < 4; ++i){
      #pragma unroll
      for (int r = 0; r < 4; ++r){
        int tl = i*16 + rq*4 + r;
        int t = m0 + tl;
        if (t < NT){
          float f = (t < fl) ? 1.f : 0.f;
          float vcv = lbn
            + wcs[tl][0]*lcn[0] + wcs[tl][1]*lcn[1]
            + wcs[tl][2]*lcn[2] + wcs[tl][3]*lcn[3]
            + wcs[tl][4]*lcn[4] + wcs[tl][5]*lcn[5]
            + wcs[tl][6]*lcn[6] + wcs[tl][7]*lcn[7];
          stc[tl][n] = f2bf(f * (acc[i][r] + lbwn + vcv));
        }
      }
    }
  }
  __syncthreads();   // stc tile complete

  // -------- phase 3: out = WoT x stc^T (512 x 64 per block), from LDS --------
  {
    f32x4 acc2[2][4] = {};
    for (int kt = 0; kt < 8; ++kt){
      int k0 = kt*32;
      bf16x8 afr[2], bfr[4];
      #pragma unroll
      for (int j = 0; j < 4; ++j)
        bfr[j] = *(const bf16x8*)(&stc[j*16 + col][k0 + kg4*8]);
      #pragma unroll
      for (int i = 0; i < 2; ++i)
        afr[i] = *(const bf16x8*)(WoT + ((size_t)(wave*32 + i*16 + col))*ND + k0 + kg4*8);
      #pragma unroll
      for (int i = 0; i < 2; ++i)
        #pragma unroll
        for (int j = 0; j < 4; ++j)
          acc2[i][j] = __builtin_amdgcn_mfma_f32_16x16x32_bf16(afr[i], bfr[j], acc2[i][j], 0, 0, 0);
    }
    int rq = lane >> 4;
    #pragma unroll
    for (int i = 0; i < 2; ++i){
      #pragma unroll
      for (int r = 0; r < 4; ++r){
        int s = wave*32 + i*16 + rq*4 + r;
        float bov = bo[s];
        #pragma unroll
        for (int j = 0; j < 4; ++j){
          int t = m0 + j*16 + col;
          if (t < NT){
            float v = acc2[i][j][r] + bov;
            if (s < ND) o_mean[((size_t)b*ND + s)*NT + t] = v;
            else        o_lstd[((size_t)b*ND + (s - ND))*NT + t] = v;
          }
        }
      }
    }
  }
}

extern "C" void kernel_launch(void* const* d_in, const int* in_sizes, int n_in,
                              void* d_out, int out_size, void* d_ws, size_t ws_size,
                              hipStream_t stream)
{
  const float* dur = (const float*)d_in[0];
  const float* ph  = (const float*)d_in[1];
  // d_in[2] phoneme_mask: unused (pm == durations > 0)
  const float* Wpw = (const float*)d_in[3];
  const float* bpw = (const float*)d_in[4];
  const float* Cw  = (const float*)d_in[5];
  const float* cbw = (const float*)d_in[6];
  const float* Mw  = (const float*)d_in[7];
  const float* mbw = (const float*)d_in[8];
  const float* Lw  = (const float*)d_in[9];
  const float* lbw = (const float*)d_in[10];
  const float* Wpc = (const float*)d_in[11];
  const float* bpc = (const float*)d_in[12];
  const float* Cc  = (const float*)d_in[13];
  const float* cbc = (const float*)d_in[14];
  const float* Mc  = (const float*)d_in[15];
  const float* mbc = (const float*)d_in[16];
  const float* Lc  = (const float*)d_in[17];
  const float* lbc = (const float*)d_in[18];
  const float* Wo  = (const float*)d_in[19];
  const float* bo  = (const float*)d_in[20];

  float* out    = (float*)d_out;
  float* o_mean = out;
  float* o_lstd = out + (size_t)NB*ND*NT;
  float* o_fm   = o_lstd + (size_t)NB*ND*NT;
  float* o_fl   = o_fm + NB*NT;
  float* o_w    = o_fl + NB;

  float* ws   = (float*)d_ws;
  float* Ew   = ws + OFF_EW;
  float* Ec   = ws + OFF_EC;
  float* bw2  = ws + OFF_BW2;
  float* bc2  = ws + OFF_BC2;
  int*   fl   = (int*)(ws + OFF_FL);
  ushort_t* Gt   = (ushort_t*)(ws + OFF_GT);
  ushort_t* WoT  = (ushort_t*)(ws + OFF_WOT);
  float4*   base = (float4*)(ws + OFF_BASE);

  k_stage1<<<64, 256, 0, stream>>>(dur, Wpw, Cw, bpw, Wpc, Cc, bpc,
                                   fl, o_fm, o_fl, Ew, Ec, bw2, bc2);
  k_stage2<<<640, 256, 0, stream>>>(dur, ph, Ew, Ec, bw2, bc2, cbw, cbc,
                                    Mw, mbw, Mc, mbc, Lw, Wo, base, Gt, WoT);
  {
    dim3 g(NB, 16);   // flat id = b + 16*ttile  ->  XCD(id%8) = b%8
    k_wv_fused<<<g, 1024, 0, stream>>>(base, fl, Mw, Mc, Gt, Lc, lbc, lbw,
                                       WoT, bo, o_w, o_mean, o_lstd);
  }
}